// Round 9
// baseline (170.484 us; speedup 1.0000x reference)
//
#include <hip/hip_runtime.h>
#include <hip/hip_bf16.h>
#include <math.h>

#define LTOK 512
#define DDIM 512
#define NEXP 32
#define HDIM 512

typedef __attribute__((ext_vector_type(8))) short short8;
typedef __attribute__((ext_vector_type(4))) float floatx4;

// round-to-nearest-even fp32->bf16, packed pair: low16 = rne(a), high16 = rne(b)
__device__ __forceinline__ unsigned bpack(float a, float b) {
    unsigned ua = __float_as_uint(a), ub = __float_as_uint(b);
    ua += 0x7FFFu + ((ua >> 16) & 1u);
    ub += 0x7FFFu + ((ub >> 16) & 1u);
    return (ua >> 16) | (ub & 0xFFFF0000u);
}

// Async global->LDS DMA (zero VGPR cost). LDS dst = wave-uniform base + lane*size.
__device__ __forceinline__ void stage16(const float* g, void* l) {
    __builtin_amdgcn_global_load_lds(
        (const __attribute__((address_space(1))) void*)g,
        (__attribute__((address_space(3))) void*)l, 16, 0, 0);
}
__device__ __forceinline__ void stage4(const float* g, void* l) {
    __builtin_amdgcn_global_load_lds(
        (const __attribute__((address_space(1))) void*)g,
        (__attribute__((address_space(3))) void*)l, 4, 0, 0);
}

// ws layout (bytes):
//   [0, 4K)        easgn: int[1024]   easgn[2t+k] = expert of token t's k-th pick
//   [4K, 8K)       wts:   float[1024] = routing weight * per_expert_scale
//   [8K, +512K)    xb:    512x512 bf16 (x rounded to bf16)

__global__ __launch_bounds__(64) void router_kernel(
    const float* __restrict__ x, const float* __restrict__ rs,
    const float* __restrict__ Wr, const float* __restrict__ pes,
    int* __restrict__ easgn, float* __restrict__ wts,
    short* __restrict__ xb, float* __restrict__ out)
{
    const int t = blockIdx.x;
    const int lane = threadIdx.x;

    float xv[8];
    float ss = 0.f;
#pragma unroll
    for (int j = 0; j < 8; ++j) {
        xv[j] = x[t * DDIM + j * 64 + lane];
        ss += xv[j] * xv[j];
    }
    // emit bf16 copy of x for the expert GEMMs; zero this token's out row
#pragma unroll
    for (int j = 0; j < 8; ++j) {
        xb[t * DDIM + j * 64 + lane] = (short)(bpack(xv[j], 0.f) & 0xFFFFu);
        out[t * DDIM + j * 64 + lane] = 0.f;
    }

#pragma unroll
    for (int o = 32; o > 0; o >>= 1) ss += __shfl_xor(ss, o);
    const float var = ss * (1.0f / 512.0f);
    const float coef = rsqrtf(var + 1e-6f) * rsqrtf(512.0f);

    __shared__ float ri[DDIM];
#pragma unroll
    for (int j = 0; j < 8; ++j) {
        const int d = j * 64 + lane;
        ri[d] = xv[j] * coef * rs[d];
    }
    __syncthreads();

    // logits: lane&31 -> expert, lane>>5 -> half of D; 4 partial accs break the chain
    const int e = lane & 31;
    const int half = lane >> 5;
    const int dbeg = half * 256;
    float l0 = 0.f, l1 = 0.f, l2 = 0.f, l3 = 0.f;
#pragma unroll 4
    for (int d = dbeg; d < dbeg + 256; d += 4) {
        l0 = fmaf(ri[d + 0], Wr[(d + 0) * NEXP + e], l0);
        l1 = fmaf(ri[d + 1], Wr[(d + 1) * NEXP + e], l1);
        l2 = fmaf(ri[d + 2], Wr[(d + 2) * NEXP + e], l2);
        l3 = fmaf(ri[d + 3], Wr[(d + 3) * NEXP + e], l3);
    }
    float lg = (l0 + l1) + (l2 + l3);
    lg += __shfl_xor(lg, 32);

    __shared__ float lgs[NEXP];
    if (lane < 32) lgs[lane] = lg;
    __syncthreads();

    if (lane == 0) {
        int i0 = 0; float m0 = lgs[0];
        for (int i = 1; i < NEXP; ++i) if (lgs[i] > m0) { m0 = lgs[i]; i0 = i; }
        int i1 = -1; float m1 = -1e30f;
        for (int i = 0; i < NEXP; ++i) if (i != i0 && lgs[i] > m1) { m1 = lgs[i]; i1 = i; }
        // softmax denom cancels against renorm: weights depend only on top-2 logits
        const float e1 = expf(m1 - m0);
        const float inv = 1.0f / (1.0f + e1);
        easgn[2 * t]     = i0;
        easgn[2 * t + 1] = i1;
        wts[2 * t]     = inv * pes[i0];
        wts[2 * t + 1] = e1 * inv * pes[i1];
    }
}

// Fused expert kernel, K-chunk decomposition (no barrier, no global act):
// block = (expert e, 32-h chunk). gates: act_win[32 slots][32 h] =
// glu(x @ G[e,:,chunk,:]^T) * wts  (LDS); linear partial: out += act_win @
// Wl[e][chunk,:]  (K=32 = one MFMA step, 8 n-tiles/wave). Weights acquired via
// 3 LDS-DMA staging rounds (16 KB/wave each, zero VGPR cost -> 128 KB/CU in
// flight; fixes R7's 1.4 TB/s register-preload choke) reusing one region, then
// packed to registers (Bg 64 + Bl 32 VGPRs). Stage region overlaid by
// toks/red/act_win after final pack. 64 KB LDS -> 2 blocks/CU.
__global__ __launch_bounds__(256, 2) void expert_kernel(
    const short* __restrict__ xb, const float* __restrict__ G,
    const float* __restrict__ Wl, const int* __restrict__ easgn,
    const float* __restrict__ wts, float* __restrict__ out)
{
    const int e  = blockIdx.y;
    const int h0 = blockIdx.x * 32;
    const int tid = threadIdx.x;
    const int wv   = tid >> 6;
    const int g    = wv & 1;    // gate index (gates GEMM)
    const int kh   = wv >> 1;   // K half (gates GEMM)
    const int lane = tid & 63;
    const int n    = lane & 15;
    const int quad = lane >> 4;

    __shared__ __align__(16) char smem[65536];
    char* const swv = smem + wv * 16384;   // per-wave 16 KB stage region
    // overlays (valid after final pack + barrier):
    int*   toks = (int*)smem;                                        // 2 KB
    float* wsl  = (float*)(smem + 2048);                             // 2 KB
    int*   lcnt = (int*)(smem + 4096);
    float (*red)[2][2][4][64] = (float(*)[2][2][4][64])(smem + 4352); // 16 KB
    short (*act_win)[40] = (short(*)[40])(smem + 20736);              // 2.5 KB

    const int4 eg = ((const int4*)easgn)[tid];   // slots 4*tid .. 4*tid+3

    // ---- G staging: 2 rounds (n-tiles), fragment-order gather (R8 pattern) ----
    const float* Gl = G + ((size_t)((e * 2 + g) * HDIM) + h0 + n) * DDIM + kh * 256 + quad * 8;
    short8 Bg[2][8];
#pragma unroll
    for (int nt = 0; nt < 2; ++nt) {
        const float* Gnt = Gl + (size_t)(nt * 16) * DDIM;
#pragma unroll
        for (int ks = 0; ks < 8; ++ks) {
#pragma unroll
            for (int half = 0; half < 2; ++half)
                stage16(Gnt + ks * 32 + half * 4, swv + (ks * 2 + half) * 1024);
        }
        __builtin_amdgcn_s_waitcnt(0x0f70);   // vmcnt(0): own DMA landed
#pragma unroll
        for (int ks = 0; ks < 8; ++ks) {
            const floatx4 u0 = *(const floatx4*)(swv + ks * 2048 + lane * 16);
            const floatx4 u1 = *(const floatx4*)(swv + ks * 2048 + 1024 + lane * 16);
            union { short8 s; unsigned u[4]; } B;
            B.u[0] = bpack(u0.x, u0.y);
            B.u[1] = bpack(u0.z, u0.w);
            B.u[2] = bpack(u1.x, u1.y);
            B.u[3] = bpack(u1.z, u1.w);
            Bg[nt][ks] = B.s;
        }
        __syncthreads();   // pack reads retired before next round's DMA overwrite
    }

    // ---- Wl staging: wave owns 32 h-rows x 128 d-cols (16 KB), stride-row gather ----
    const float* Wbase = Wl + ((size_t)e * HDIM + h0 + quad * 8) * DDIM + wv * 128 + n;
    short8 Bl[8];
#pragma unroll
    for (int nt2 = 0; nt2 < 8; ++nt2) {
#pragma unroll
        for (int j = 0; j < 8; ++j)
            stage4(Wbase + (size_t)j * DDIM + nt2 * 16, swv + (nt2 * 8 + j) * 256);
    }
    __builtin_amdgcn_s_waitcnt(0x0f70);   // vmcnt(0)
#pragma unroll
    for (int nt2 = 0; nt2 < 8; ++nt2) {
        float w[8];
#pragma unroll
        for (int j = 0; j < 8; ++j)
            w[j] = *(const float*)(swv + (nt2 * 8 + j) * 256 + lane * 4);
        union { short8 s; unsigned u[4]; } B;
        B.u[0] = bpack(w[0], w[1]);
        B.u[1] = bpack(w[2], w[3]);
        B.u[2] = bpack(w[4], w[5]);
        B.u[3] = bpack(w[6], w[7]);
        Bl[nt2] = B.s;
    }
    __syncthreads();   // stage dead; overlays legal

    // ---- self-select scan ----
    if (tid == 0) *lcnt = 0;
    __syncthreads();
    if (eg.x == e) { int p = atomicAdd(lcnt, 1); toks[p] = 4 * tid;     wsl[p] = wts[4 * tid]; }
    if (eg.y == e) { int p = atomicAdd(lcnt, 1); toks[p] = 4 * tid + 1; wsl[p] = wts[4 * tid + 1]; }
    if (eg.z == e) { int p = atomicAdd(lcnt, 1); toks[p] = 4 * tid + 2; wsl[p] = wts[4 * tid + 2]; }
    if (eg.w == e) { int p = atomicAdd(lcnt, 1); toks[p] = 4 * tid + 3; wsl[p] = wts[4 * tid + 3]; }
    __syncthreads();
    const int Ne = *lcnt;
    if (Ne == 0) return;

    const short* xbh = xb + kh * 256;

    for (int mb = 0; mb < Ne; mb += 32) {
        int arow[2];
#pragma unroll
        for (int i = 0; i < 2; ++i) {
            int s = mb + i * 16 + n;
            arow[i] = toks[s < Ne ? s : Ne - 1] >> 1;   // token index
        }

        // ---- gates GEMM: acc[m][nt], K-half kh, gate g ----
        floatx4 acc[2][2] = {};
#pragma unroll
        for (int ks = 0; ks < 8; ++ks) {
            const int ko = ks * 32 + quad * 8;
#pragma unroll
            for (int i = 0; i < 2; ++i) {
                const short8 A = *(const short8*)(xbh + (size_t)arow[i] * DDIM + ko);
#pragma unroll
                for (int nt = 0; nt < 2; ++nt)
                    acc[i][nt] = __builtin_amdgcn_mfma_f32_16x16x32_bf16(A, Bg[nt][ks], acc[i][nt], 0, 0, 0);
            }
        }
#pragma unroll
        for (int i = 0; i < 2; ++i)
#pragma unroll
            for (int nt = 0; nt < 2; ++nt)
#pragma unroll
                for (int r = 0; r < 4; ++r)
                    red[wv][i][nt][r][lane] = acc[i][nt][r];
        __syncthreads();

        // ---- glu epilogue -> act_win (wave handles pair m=wv&1, nt=wv>>1) ----
        // C/D: col = lane&15 (h), row = quad*4 + r (slot)
        {
            const int m  = wv & 1;
            const int nt = wv >> 1;
#pragma unroll
            for (int r = 0; r < 4; ++r) {
                const int s = mb + m * 16 + quad * 4 + r;
                if (s < Ne) {
                    const float g0 = red[0][m][nt][r][lane] + red[2][m][nt][r][lane];
                    const float g1 = red[1][m][nt][r][lane] + red[3][m][nt][r][lane];
                    // gelu_tanh(g0) = g0 * sigmoid(2*u)
                    const float uu = 0.7978845608f * (g0 + 0.044715f * g0 * g0 * g0);
                    const float sg = 1.0f / (1.0f + __expf(-2.0f * uu));
                    const float v = g0 * sg * g1 * wsl[s];   // routing scale folded in
                    act_win[m * 16 + quad * 4 + r][nt * 16 + n] = (short)(bpack(v, 0.f) & 0xFFFFu);
                }
            }
        }
        __syncthreads();

        // ---- linear partial: out[:, wv*128 + nt2*16 + n] += act_win @ Bl ----
        // A: row = lane&15 (slot), k = quad*8+j (h-local, K=32 exactly)
#pragma unroll
        for (int i = 0; i < 2; ++i) {
            const short8 Aw = *(const short8*)&act_win[i * 16 + n][quad * 8];
#pragma unroll
            for (int nt2 = 0; nt2 < 8; ++nt2) {
                floatx4 y = {};
                y = __builtin_amdgcn_mfma_f32_16x16x32_bf16(Aw, Bl[nt2], y, 0, 0, 0);
#pragma unroll
                for (int r = 0; r < 4; ++r) {
                    const int s = mb + i * 16 + quad * 4 + r;
                    if (s < Ne)
                        atomicAdd(&out[(size_t)(toks[s] >> 1) * DDIM + wv * 128 + nt2 * 16 + n], y[r]);
                }
            }
        }
        __syncthreads();   // protect red/act_win before next window
    }
}

extern "C" void kernel_launch(void* const* d_in, const int* in_sizes, int n_in,
                              void* d_out, int out_size, void* d_ws, size_t ws_size,
                              hipStream_t stream)
{
    const float* x   = (const float*)d_in[0];
    const float* rs  = (const float*)d_in[1];
    const float* Wr  = (const float*)d_in[2];
    const float* G   = (const float*)d_in[3];
    const float* Wl  = (const float*)d_in[4];
    const float* pes = (const float*)d_in[5];
    float* out = (float*)d_out;

    char* ws = (char*)d_ws;
    int*   easgn = (int*)(ws);
    float* wts   = (float*)(ws + 4096);
    short* xb    = (short*)(ws + 8192);

    router_kernel<<<dim3(LTOK), dim3(64), 0, stream>>>(x, rs, Wr, pes, easgn, wts, xb, out);
    expert_kernel<<<dim3(16, NEXP), dim3(256), 0, stream>>>(xb, G, Wl, easgn, wts, out);
}